// Round 18
// baseline (36.420 us; speedup 1.0000x reference)
//
#include <hip/hip_runtime.h>

#define B_ 32
#define N_ 4096
#define M_ 32
#define F_ 256
#define A_ 8

typedef float f32x4 __attribute__((ext_vector_type(4)));
typedef int   i32x4 __attribute__((ext_vector_type(4)));

// workspace layout:
//   floats [0, 4*B*A*F)      anchor_feat K-partials [kpart][b*A+k][F]
//   bytes  at WS_FLAGS_F     per-row 8-bit anchor-hit mask (B*N bytes)
#define WS_PART 0
#define WS_FLAGS_F (4 * B_ * A_ * F_)

// ---- kernel 1 (node 1): K-split anchor partials || agraph mask-scan ----
// e1 = h@(a1+a2) is provably irrelevant: e[b,n,k] = e1[b,n] + e2[b,k] and
// softmax over k is invariant to the per-row constant e1 (masked entries are
// -1e9 absolute; exp underflows to 0 either way; all-masked -> uniform 1/8).
// Anchor GEMM split 4x over K (64-deep chains, no 256-deep latency tail);
// partials combined (and e2 derived) in node 2's latency-hidden preamble.
#define ANCHOR_BLOCKS (4 * B_ * A_)      // 1024
#define MASK_BLOCKS (B_ * N_ / 256)      // 512

__global__ __launch_bounds__(256) void prep_kernel(const float* __restrict__ fatoms,
                                                   const int* __restrict__ agraph,
                                                   const int* __restrict__ anchor_idx,
                                                   const float* __restrict__ W,
                                                   float* __restrict__ ws,
                                                   unsigned char* __restrict__ flags) {
    int tid = threadIdx.x;

    if (blockIdx.x < (unsigned)ANCHOR_BLOCKS) {
        // ---- anchor partial: part[pk][bk][tid] = sum_{i in 64pk..} xs_i W[i][tid]
        int pk = blockIdx.x & 3;
        int bk = blockIdx.x >> 2;      // b*A_ + k
        int b  = bk >> 3;
        __shared__ float xs[64];
        int idx = anchor_idx[bk];
        if (tid < 64) xs[tid] = fatoms[((size_t)b * N_ + idx) * F_ + pk * 64 + tid];
        __syncthreads();
        float acc[4] = {0.f, 0.f, 0.f, 0.f};
        const float* wbase = W + (size_t)(pk * 64) * F_ + tid;
        for (int i0 = 0; i0 < 64; i0 += 16) {
#pragma unroll
            for (int j = 0; j < 16; ++j)
                acc[j & 3] += xs[i0 + j] * wbase[(size_t)(i0 + j) * F_];  // coalesced
        }
        ws[WS_PART + ((size_t)pk * B_ * A_ + bk) * F_ + tid] =
            (acc[0] + acc[1]) + (acc[2] + acc[3]);
    } else {
        // ---- mask part: one row per thread; write 8-bit hit mask ----
        int mb   = blockIdx.x - ANCHOR_BLOCKS;  // 0..511
        int b    = mb >> 4;                     // 16 blocks per batch
        int gidx = mb * 256 + tid;              // == b*N + row

        int anch[A_];
#pragma unroll
        for (int k = 0; k < A_; ++k) anch[k] = anchor_idx[b * A_ + k];

        const i32x4* gp = (const i32x4*)(agraph + (size_t)gidx * M_);
        i32x4 g[M_ / 4];
#pragma unroll
        for (int j = 0; j < M_ / 4; ++j) g[j] = gp[j];

        unsigned mk = 0;
#pragma unroll
        for (int j = 0; j < M_ / 4; ++j) {
#pragma unroll
            for (int k = 0; k < A_; ++k) {
                int hit = (g[j].x == anch[k]) | (g[j].y == anch[k]) |
                          (g[j].z == anch[k]) | (g[j].w == anch[k]);
                mk |= hit ? (1u << k) : 0u;
            }
        }
        flags[gidx] = (unsigned char)mk;
    }
}

// ---- kernel 2 (node 2): fill-like streaming store ----------------------
// 512 blocks x 256 threads; wave w owns 64 consecutive rows. Preamble:
// combine 4 K-partials -> afr, derive e2 via wave reduction (hidden under
// the store stream), then 16x {scalar flag dword -> 4x1KB stores}.
__global__ __launch_bounds__(256) void stream_kernel(const float* __restrict__ ws,
                                                     const unsigned char* __restrict__ flags,
                                                     const float* __restrict__ a,
                                                     float* __restrict__ out) {
    int tid  = threadIdx.x;
    int w    = __builtin_amdgcn_readfirstlane(tid >> 6);  // wave id -> SGPR
    int lane = tid & 63;
    int b    = blockIdx.x >> 4;                    // 16 blocks per batch
    int row0 = ((int)(blockIdx.x & 15) * 4 + w) * 64;

    // afr[k] = sum of 4 K-partials for this lane's 4 features
    f32x4 afr[A_];
#pragma unroll
    for (int k = 0; k < A_; ++k) {
        const float* p0 = ws + WS_PART + (size_t)(b * A_ + k) * F_ + lane * 4;
        f32x4 t = *(const f32x4*)p0;
        t += *(const f32x4*)(p0 + (size_t)1 * B_ * A_ * F_);
        t += *(const f32x4*)(p0 + (size_t)2 * B_ * A_ * F_);
        t += *(const f32x4*)(p0 + (size_t)3 * B_ * A_ * F_);
        afr[k] = t;
    }

    // e2[k] = sum_f afr-row . (a1-a2): per-wave butterfly (all lanes get total)
    f32x4 dd = *(const f32x4*)(a + lane * 4) - *(const f32x4*)(a + F_ + lane * 4);
    float e2r[A_];
#pragma unroll
    for (int k = 0; k < A_; ++k) {
        float part = afr[k].x * dd.x + afr[k].y * dd.y +
                     afr[k].z * dd.z + afr[k].w * dd.w;
#pragma unroll
        for (int off = 32; off > 0; off >>= 1) part += __shfl_xor(part, off);
        e2r[k] = part;
    }
    float m8 = e2r[0];
#pragma unroll
    for (int k = 1; k < A_; ++k) m8 = fmaxf(m8, e2r[k]);
    float E[A_];
#pragma unroll
    for (int k = 0; k < A_; ++k) E[k] = __expf(e2r[k] - m8);

    // uniform-row constant: afm = (sum_k afr[k]) / 8  (exact)
    f32x4 afm = ((afr[0] + afr[1]) + (afr[2] + afr[3])) +
                ((afr[4] + afr[5]) + (afr[6] + afr[7]));
    afm *= 0.125f;

    // preload all 16 flag dwords for this wave's 64 rows (scalar burst)
    const unsigned* fb = (const unsigned*)(flags + (size_t)b * N_ + row0);
    unsigned f16[16];
#pragma unroll
    for (int j = 0; j < 16; ++j) f16[j] = fb[j];

    size_t base = ((size_t)b * N_ + row0) * F_ + lane * 4;
    for (int r0 = 0; r0 < 64; r0 += 4) {
        unsigned f4 = f16[r0 >> 2];
        f32x4 o[4];
        if (f4 == 0) {  // ~78% of groups: pure constant store
#pragma unroll
            for (int u = 0; u < 4; ++u) o[u] = afm;
        } else {
#pragma unroll
            for (int u = 0; u < 4; ++u) {
                unsigned mku = (f4 >> (8 * u)) & 0xffu;
                if (mku) {
                    float p[A_], s = 0.f;
#pragma unroll
                    for (int k = 0; k < A_; ++k) {
                        p[k] = (mku & (1u << k)) ? E[k] : 0.f;
                        s += p[k];
                    }
                    float rinv = __builtin_amdgcn_rcpf(s);
                    f32x4 t = (p[0] * rinv) * afr[0];
                    t += (p[1] * rinv) * afr[1];
                    t += (p[2] * rinv) * afr[2];
                    t += (p[3] * rinv) * afr[3];
                    t += (p[4] * rinv) * afr[4];
                    t += (p[5] * rinv) * afr[5];
                    t += (p[6] * rinv) * afr[6];
                    t += (p[7] * rinv) * afr[7];
                    o[u] = t;
                } else {
                    o[u] = afm;
                }
            }
        }
#pragma unroll
        for (int u = 0; u < 4; ++u)
            *(f32x4*)(out + base + (size_t)(r0 + u) * F_) = o[u];
    }
}

extern "C" void kernel_launch(void* const* d_in, const int* in_sizes, int n_in,
                              void* d_out, int out_size, void* d_ws, size_t ws_size,
                              hipStream_t stream) {
    const float* fatoms     = (const float*)d_in[0];
    const int*   agraph     = (const int*)d_in[1];
    const int*   anchor_idx = (const int*)d_in[2];
    const float* W          = (const float*)d_in[3];
    const float* a          = (const float*)d_in[4];
    float*       out        = (float*)d_out;
    float*       ws         = (float*)d_ws;
    unsigned char* flags    = (unsigned char*)(ws + WS_FLAGS_F);

    hipLaunchKernelGGL(prep_kernel, dim3(ANCHOR_BLOCKS + MASK_BLOCKS), dim3(256), 0,
                       stream, fatoms, agraph, anchor_idx, W, ws, flags);
    hipLaunchKernelGGL(stream_kernel, dim3(B_ * (N_ / 256)), dim3(256), 0, stream,
                       ws, flags, a, out);
}

// Round 19
// 35.572 us; speedup vs baseline: 1.0239x; 1.0239x over previous
//
#include <hip/hip_runtime.h>

#define B_ 32
#define N_ 4096
#define M_ 32
#define F_ 256
#define A_ 8

typedef float f32x4 __attribute__((ext_vector_type(4)));
typedef int   i32x4 __attribute__((ext_vector_type(4)));

// workspace layout:
//   floats [0, B*A*F)        anchor_feat (B,A,F)
//   floats [WS_E2, +B*A)     e2 = anchor_feat @ (a1-a2)
//   bytes  at WS_FLAGS_F     per-row 8-bit anchor-hit mask (B*N bytes)
#define WS_AF 0
#define WS_E2 (B_ * A_ * F_)
#define WS_FLAGS_F (WS_E2 + B_ * A_)

// ---- kernel 1 (node 1): anchor GEMM blocks || agraph mask-scan blocks ----
// Independent block ranges, no cross-block communication (R10/R11 lesson).
// e1 = h@(a1+a2) is provably irrelevant: e[b,n,k] = e1[b,n] + e2[b,k] and
// softmax over k is invariant to the per-row constant e1 (masked entries are
// -1e9 absolute; exp underflows to 0 either way; all-masked -> uniform 1/8).
#define MASK_BLOCKS (B_ * N_ / 256)  // 512

__global__ __launch_bounds__(256) void prep_kernel(const float* __restrict__ fatoms,
                                                   const int* __restrict__ agraph,
                                                   const int* __restrict__ anchor_idx,
                                                   const float* __restrict__ W,
                                                   const float* __restrict__ a,
                                                   float* __restrict__ ws,
                                                   unsigned char* __restrict__ flags) {
    int tid = threadIdx.x;

    if (blockIdx.x < (unsigned)(B_ * A_)) {
        // ---- anchor part: anchor_feat[bk] + e2[bk] ----
        int bk = blockIdx.x;
        int b  = bk / A_;
        __shared__ float xs[F_];
        __shared__ float red[F_];
        int idx = anchor_idx[bk];
        xs[tid] = fatoms[((size_t)b * N_ + idx) * F_ + tid];
        __syncthreads();
        float acc[4] = {0.f, 0.f, 0.f, 0.f};
        for (int i0 = 0; i0 < F_; i0 += 16) {
#pragma unroll
            for (int j = 0; j < 16; ++j)
                acc[j & 3] += xs[i0 + j] * W[(i0 + j) * F_ + tid];  // coalesced
        }
        float accs = (acc[0] + acc[1]) + (acc[2] + acc[3]);
        ws[WS_AF + bk * F_ + tid] = accs;
        red[tid] = accs * (a[tid] - a[tid + F_]);
        __syncthreads();
        for (int s = 128; s > 0; s >>= 1) {
            if (tid < s) red[tid] += red[tid + s];
            __syncthreads();
        }
        if (tid == 0) ws[WS_E2 + bk] = red[0];
    } else {
        // ---- mask part: one row per thread; write 8-bit hit mask ----
        int mb   = blockIdx.x - B_ * A_;   // 0..511
        int b    = mb >> 4;                // 16 blocks per batch
        int gidx = mb * 256 + tid;         // == b*N + row (rows in order)

        int anch[A_];
#pragma unroll
        for (int k = 0; k < A_; ++k) anch[k] = anchor_idx[b * A_ + k];

        const i32x4* gp = (const i32x4*)(agraph + (size_t)gidx * M_);
        i32x4 g[M_ / 4];
#pragma unroll
        for (int j = 0; j < M_ / 4; ++j) g[j] = gp[j];

        unsigned mk = 0;
#pragma unroll
        for (int j = 0; j < M_ / 4; ++j) {
#pragma unroll
            for (int k = 0; k < A_; ++k) {
                int hit = (g[j].x == anch[k]) | (g[j].y == anch[k]) |
                          (g[j].z == anch[k]) | (g[j].w == anch[k]);
                mk |= hit ? (1u << k) : 0u;
            }
        }
        flags[gidx] = (unsigned char)mk;
    }
}

// ---- kernel 2 (node 2): fill-like streaming store ----------------------
// Fill-kernel geometry: 512 blocks x 256 threads (4 waves); wave w owns 64
// consecutive rows. All 16 flag dwords preloaded via scalar loads up front
// (no load->branch->store serialization).
__global__ __launch_bounds__(256) void stream_kernel(const float* __restrict__ ws,
                                                     const unsigned char* __restrict__ flags,
                                                     float* __restrict__ out) {
    int tid  = threadIdx.x;
    int w    = __builtin_amdgcn_readfirstlane(tid >> 6);  // wave id -> SGPR
    int lane = tid & 63;
    int b    = blockIdx.x >> 4;                    // 512 blocks: 16 per batch
    int row0 = ((int)(blockIdx.x & 15) * 4 + w) * 64;

    const float* af = ws + WS_AF + b * (A_ * F_);
    f32x4 afr[A_];
#pragma unroll
    for (int k = 0; k < A_; ++k) afr[k] = *(const f32x4*)(af + k * F_ + lane * 4);

    float e2r[A_];
#pragma unroll
    for (int k = 0; k < A_; ++k) e2r[k] = ws[WS_E2 + b * A_ + k];
    float m8 = e2r[0];
#pragma unroll
    for (int k = 1; k < A_; ++k) m8 = fmaxf(m8, e2r[k]);
    float E[A_];
#pragma unroll
    for (int k = 0; k < A_; ++k) E[k] = __expf(e2r[k] - m8);

    // uniform-row constant: afm = (sum_k afr[k]) / 8  (exact)
    f32x4 afm = ((afr[0] + afr[1]) + (afr[2] + afr[3])) +
                ((afr[4] + afr[5]) + (afr[6] + afr[7]));
    afm *= 0.125f;

    // preload all 16 flag dwords for this wave's 64 rows (scalar burst)
    const unsigned* fb = (const unsigned*)(flags + (size_t)b * N_ + row0);
    unsigned f16[16];
#pragma unroll
    for (int j = 0; j < 16; ++j) f16[j] = fb[j];

    size_t base = ((size_t)b * N_ + row0) * F_ + lane * 4;
    for (int r0 = 0; r0 < 64; r0 += 4) {
        unsigned f4 = f16[r0 >> 2];
        f32x4 o[4];
        if (f4 == 0) {  // ~78% of groups: pure constant store
#pragma unroll
            for (int u = 0; u < 4; ++u) o[u] = afm;
        } else {
#pragma unroll
            for (int u = 0; u < 4; ++u) {
                unsigned mku = (f4 >> (8 * u)) & 0xffu;
                if (mku) {
                    float p[A_], s = 0.f;
#pragma unroll
                    for (int k = 0; k < A_; ++k) {
                        p[k] = (mku & (1u << k)) ? E[k] : 0.f;
                        s += p[k];
                    }
                    float rinv = __builtin_amdgcn_rcpf(s);
                    f32x4 t = (p[0] * rinv) * afr[0];
                    t += (p[1] * rinv) * afr[1];
                    t += (p[2] * rinv) * afr[2];
                    t += (p[3] * rinv) * afr[3];
                    t += (p[4] * rinv) * afr[4];
                    t += (p[5] * rinv) * afr[5];
                    t += (p[6] * rinv) * afr[6];
                    t += (p[7] * rinv) * afr[7];
                    o[u] = t;
                } else {
                    o[u] = afm;
                }
            }
        }
#pragma unroll
        for (int u = 0; u < 4; ++u)
            *(f32x4*)(out + base + (size_t)(r0 + u) * F_) = o[u];
    }
}

extern "C" void kernel_launch(void* const* d_in, const int* in_sizes, int n_in,
                              void* d_out, int out_size, void* d_ws, size_t ws_size,
                              hipStream_t stream) {
    const float* fatoms     = (const float*)d_in[0];
    const int*   agraph     = (const int*)d_in[1];
    const int*   anchor_idx = (const int*)d_in[2];
    const float* W          = (const float*)d_in[3];
    const float* a          = (const float*)d_in[4];
    float*       out        = (float*)d_out;
    float*       ws         = (float*)d_ws;
    unsigned char* flags    = (unsigned char*)(ws + WS_FLAGS_F);

    hipLaunchKernelGGL(prep_kernel, dim3(B_ * A_ + MASK_BLOCKS), dim3(256), 0, stream,
                       fatoms, agraph, anchor_idx, W, a, ws, flags);
    hipLaunchKernelGGL(stream_kernel, dim3(B_ * (N_ / 256)), dim3(256), 0, stream,
                       ws, flags, out);
}